// Round 8
// baseline (71.830 us; speedup 1.0000x reference)
//
#include <hip/hip_runtime.h>
#include <math.h>

#define NC 200000
#define NE 500000
#define NP 100000
#define NG 256
#define NLAYERS 4
#define NKEY 256          // key = (min(n0,15)<<4) | min(n1,15)
#define CLAMP 15
#define NSLOPE 0.2f
#define R 8               // count replicas, one per XCD
#define KPB 4             // keys per block in k_layers4

// workspace layout (bytes)
#define O_CNT 0u          // R*NC ints, packed n0=lo16 n1=hi16 (6,400,000 B)
#define O_TB  6400000u    // 3125 uints: piece type bits (12,800 B)
#define O_XS  6412800u    // 4096 f32: xs[(l*2+t)*512 + h*128 + d]
#define O_GB  6429184u    // 257 ints: per-graph cell ranges
#define O_TAB 6430336u    // NKEY*128 f32

// k_prep block partition
#define ZB   1563         // zero R*NC ints (400,000 int4)
#define TBB  13           // type-bit pack blocks
#define XSB  16           // xs GEMM blocks
#define GBB  782          // boundary-scan blocks
#define PREP_BLOCKS (ZB + TBB + XSB + GBB)

__device__ __forceinline__ float lrelu(float x) { return x > 0.f ? x : NSLOPE * x; }

// prep: zero cnt replicas; pack piece type bits; xs = piece_emb@W_l+b_l;
// gb = per-graph cell ranges via boundary scan of sorted cell_batch
__global__ void k_prep(int4* __restrict__ zbase,
                       const int* __restrict__ piece_x,
                       unsigned* __restrict__ tb,
                       const float* __restrict__ piece_emb,
                       const float* __restrict__ W_l,
                       const float* __restrict__ b_l,
                       float* __restrict__ xs,
                       const int* __restrict__ cell_batch,
                       int* __restrict__ gb) {
  int b = blockIdx.x, tid = threadIdx.x;
  if (b < ZB) {
    int i4 = b * 256 + tid;
    if (i4 < (R * NC) / 4) zbase[i4] = make_int4(0, 0, 0, 0);
  } else if (b < ZB + TBB) {
    int j = (b - ZB) * 256 + tid;                 // 3125 words of 32 pieces
    if (j < NP / 32) {
      unsigned w = 0;
      const int* p = piece_x + j * 32;
      #pragma unroll
      for (int k = 0; k < 32; ++k) w |= (unsigned)(p[k] & 1) << k;
      tb[j] = w;
    }
  } else if (b < ZB + TBB + XSB) {
    int idx = (b - ZB - TBB) * 256 + tid;         // 0..4095
    int l = idx >> 10, t = (idx >> 9) & 1, j = idx & 511;
    float acc = b_l[l * 512 + j];
    const float* pe = piece_emb + t * 128;
    const float* W = W_l + l * 65536;
    #pragma unroll 8
    for (int d = 0; d < 128; ++d) acc = fmaf(pe[d], W[d * 512 + j], acc);
    xs[idx] = acc;
  } else {
    int i = (b - ZB - TBB - XSB) * 256 + tid;
    if (i < NC) {
      int bi = cell_batch[i];
      int bn = (i + 1 < NC) ? cell_batch[i + 1] : NG;
      if (i == 0) for (int g = 0; g <= bi; ++g) gb[g] = 0;
      for (int g = bi + 1; g <= bn; ++g) gb[g] = i + 1;
    }
  }
}

// count edges per dst cell (packed by type); 4 edges/thread;
// replica pinned to this wave's XCD so atomics stay in the local L2
__global__ void __launch_bounds__(256)
k_count(const unsigned* __restrict__ tb,
        const int* __restrict__ esrc,
        const int* __restrict__ edst,
        int* __restrict__ cnt) {
  unsigned xcc;
  asm volatile("s_getreg_b32 %0, hwreg(HW_REG_XCC_ID)" : "=s"(xcc));
  int* base = cnt + (xcc & (R - 1)) * NC;
  int gid = blockIdx.x * blockDim.x + threadIdx.x;
  if (gid >= NE / 4) return;
  int4 s4 = *(const int4*)(esrc + gid * 4);
  int4 d4 = *(const int4*)(edst + gid * 4);
  int t0 = (tb[s4.x >> 5] >> (s4.x & 31)) & 1;
  int t1 = (tb[s4.y >> 5] >> (s4.y & 31)) & 1;
  int t2 = (tb[s4.z >> 5] >> (s4.z & 31)) & 1;
  int t3 = (tb[s4.w >> 5] >> (s4.w & 31)) & 1;
  atomicAdd(&base[d4.x], 1 << (t0 << 4));
  atomicAdd(&base[d4.y], 1 << (t1 << 4));
  atomicAdd(&base[d4.z], 1 << (t2 << 4));
  atomicAdd(&base[d4.w], 1 << (t3 << 4));
}

// all 4 GATv2 layers, KPB keys per block; 64 blocks cover 256 keys
__global__ void __launch_bounds__(256)
k_layers4(const float* __restrict__ cell_emb,
          const float* __restrict__ W_r, const float* __restrict__ b_r,
          const float* __restrict__ xs,  const float* __restrict__ att,
          const float* __restrict__ conv_bias,
          float* __restrict__ tab) {
  __shared__ float cell[KPB][128];
  __shared__ float p[KPB][1024];    // [key][type*512 + head*128 + d]
  __shared__ float Lred[KPB][8];    // [key][type*4 + head]
  __shared__ float wgt[KPB][8];     // [key][head]=w0, [key][4+head]=w1
  int tid = threadIdx.x;
  int kbase = blockIdx.x * KPB;
  { int d = tid & 127;
    for (int kk = tid >> 7; kk < KPB; kk += 2) cell[kk][d] = cell_emb[d]; }
  __syncthreads();

  for (int l = 0; l < NLAYERS; ++l) {
    const float* Wl  = W_r + (size_t)l * 65536;
    const float* xsL = xs + l * 1024;
    const float* aL  = att + l * 512;
    float2 bb = *(const float2*)(b_r + l * 512 + 2 * tid);
    float accx[KPB], accy[KPB];
    #pragma unroll
    for (int kk = 0; kk < KPB; ++kk) { accx[kk] = bb.x; accy[kk] = bb.y; }
    #pragma unroll 4
    for (int dc = 0; dc < 32; ++dc) {
      float4 cv[KPB];
      #pragma unroll
      for (int kk = 0; kk < KPB; ++kk) cv[kk] = ((const float4*)cell[kk])[dc];
      #pragma unroll
      for (int j = 0; j < 4; ++j) {
        float2 w = *(const float2*)(Wl + (dc * 4 + j) * 512 + 2 * tid);
        #pragma unroll
        for (int kk = 0; kk < KPB; ++kk) {
          float c = j == 0 ? cv[kk].x : j == 1 ? cv[kk].y : j == 2 ? cv[kk].z : cv[kk].w;
          accx[kk] = fmaf(c, w.x, accx[kk]);
          accy[kk] = fmaf(c, w.y, accy[kk]);
        }
      }
    }
    float2 av = *(const float2*)(aL + 2 * tid);
    float2 x0 = *(const float2*)(xsL + 2 * tid);          // type0
    float2 x1 = *(const float2*)(xsL + 512 + 2 * tid);    // type1
    #pragma unroll
    for (int kk = 0; kk < KPB; ++kk) {
      *(float2*)&p[kk][2 * tid] =
        make_float2(lrelu(x0.x + accx[kk]) * av.x, lrelu(x0.y + accy[kk]) * av.y);
      *(float2*)&p[kk][512 + 2 * tid] =
        make_float2(lrelu(x1.x + accx[kk]) * av.x, lrelu(x1.y + accy[kk]) * av.y);
    }
    __syncthreads();
    int q = tid >> 5, lane = tid & 31;
    #pragma unroll
    for (int kk = 0; kk < KPB; ++kk) {
      const float* base = &p[kk][q * 128];
      float s = base[lane] + base[lane + 32] + base[lane + 64] + base[lane + 96];
      #pragma unroll
      for (int m = 16; m >= 1; m >>= 1) s += __shfl_xor(s, m);
      if (lane == 0) Lred[kk][q] = s;
    }
    __syncthreads();
    if (tid < 4 * KPB) {
      int kk = tid >> 2, h = tid & 3;
      int k = kbase + kk;
      int n0 = k >> 4, n1 = k & 15;
      float ww0 = 0.f, ww1 = 0.f;
      if (n0 + n1 > 0) {
        float L0 = Lred[kk][h], L1 = Lred[kk][4 + h];
        float m = -1e30f;
        if (n0 > 0) m = L0;
        if (n1 > 0) m = fmaxf(m, L1);
        float e0 = (n0 > 0) ? (float)n0 * expf(L0 - m) : 0.f;
        float e1 = (n1 > 0) ? (float)n1 * expf(L1 - m) : 0.f;
        float inv = 1.f / (e0 + e1);
        ww0 = e0 * inv; ww1 = e1 * inv;
      }
      wgt[kk][h] = ww0; wgt[kk][4 + h] = ww1;
    }
    __syncthreads();
    { int d = tid & 127;
      for (int kk = tid >> 7; kk < KPB; kk += 2) {
        float o = conv_bias[l * 128 + d];
        #pragma unroll
        for (int h = 0; h < 4; ++h)
          o += 0.25f * (wgt[kk][h]     * xsL[h * 128 + d] +
                        wgt[kk][4 + h] * xsL[512 + h * 128 + d]);
        o = fmaxf(o, 0.f);
        cell[kk][d] = o;
        if (l == NLAYERS - 1) tab[(kbase + kk) * 128 + d] = o;
      }
    }
    __syncthreads();
  }
}

// per-graph pool via 256-key histogram (replica-summed) + MLP head
__global__ void __launch_bounds__(256)
k_poolhead(const int* __restrict__ gb, const unsigned* __restrict__ cnt,
           const float* __restrict__ tab,
           const float* __restrict__ fc1_w, const float* __restrict__ fc1_b,
           const float* __restrict__ pol_w, const float* __restrict__ pol_b,
           const float* __restrict__ val_w, const float* __restrict__ val_b,
           float* __restrict__ out) {
  __shared__ int hist[NKEY];
  __shared__ int klist[NKEY];
  __shared__ int wcnt[4];
  __shared__ float emb[128];
  __shared__ float hbuf[64];
  int g = blockIdx.x, tid = threadIdx.x;
  hist[tid] = 0;
  __syncthreads();
  int lo = gb[g], hi = gb[g + 1];
  for (int c = lo + tid; c < hi; c += 256) {
    unsigned v = 0;
    #pragma unroll
    for (int r = 0; r < R; ++r) v += cnt[c + r * NC];
    int n0 = min((int)(v & 0xffffu), CLAMP);
    int n1 = min((int)(v >> 16), CLAMP);
    atomicAdd(&hist[(n0 << 4) | n1], 1);
  }
  __syncthreads();
  // deterministic ordered compaction of present keys
  unsigned long long m = __ballot(hist[tid] != 0);
  int w = tid >> 6, lane = tid & 63;
  if (lane == 0) wcnt[w] = __popcll(m);
  __syncthreads();
  int basep = 0;
  #pragma unroll
  for (int i = 0; i < 4; ++i) if (i < w) basep += wcnt[i];
  if (hist[tid] != 0)
    klist[basep + __popcll(m & ((1ull << lane) - 1ull))] = tid;
  __syncthreads();
  int kn = wcnt[0] + wcnt[1] + wcnt[2] + wcnt[3];
  if (tid < 128) {
    float acc = 0.f;
    for (int i = 0; i < kn; ++i) {
      int k = klist[i];
      acc = fmaf((float)hist[k], tab[k * 128 + tid], acc);
    }
    emb[tid] = acc / fmaxf((float)(hi - lo), 1.f);
  }
  __syncthreads();
  if (tid < 64) {
    float a = fc1_b[tid];
    #pragma unroll 8
    for (int d = 0; d < 128; ++d) a = fmaf(emb[d], fc1_w[d * 64 + tid], a);
    hbuf[tid] = fmaxf(a, 0.f);
  }
  __syncthreads();
  if (tid < 8) {
    float p = pol_b[tid];
    #pragma unroll
    for (int k = 0; k < 64; ++k) p = fmaf(hbuf[k], pol_w[k * 8 + tid], p);
    out[g * 8 + tid] = p;
  } else if (tid == 8) {
    float v = val_b[0];
    #pragma unroll
    for (int k = 0; k < 64; ++k) v = fmaf(hbuf[k], val_w[k], v);
    out[NG * 8 + g] = tanhf(v);
  }
}

extern "C" void kernel_launch(void* const* d_in, const int* in_sizes, int n_in,
                              void* d_out, int out_size, void* d_ws, size_t ws_size,
                              hipStream_t stream) {
  (void)in_sizes; (void)n_in; (void)out_size; (void)ws_size;
  const int*   piece_x   = (const int*)d_in[1];
  const int*   edge_src  = (const int*)d_in[2];
  const int*   edge_dst  = (const int*)d_in[3];
  const int*   cell_batch= (const int*)d_in[4];
  const float* cell_emb  = (const float*)d_in[5];
  const float* piece_emb = (const float*)d_in[6];
  const float* W_l       = (const float*)d_in[7];
  const float* b_l       = (const float*)d_in[8];
  const float* W_r       = (const float*)d_in[9];
  const float* b_r       = (const float*)d_in[10];
  const float* att       = (const float*)d_in[11];
  const float* conv_bias = (const float*)d_in[12];
  const float* fc1_w     = (const float*)d_in[13];
  const float* fc1_b     = (const float*)d_in[14];
  const float* pol_w     = (const float*)d_in[15];
  const float* pol_b     = (const float*)d_in[16];
  const float* val_w     = (const float*)d_in[17];
  const float* val_b     = (const float*)d_in[18];
  float* out = (float*)d_out;

  char* ws = (char*)d_ws;
  int*      cnt  = (int*)(ws + O_CNT);
  unsigned* cntu = (unsigned*)(ws + O_CNT);
  unsigned* tb   = (unsigned*)(ws + O_TB);
  float*    xs   = (float*)(ws + O_XS);
  int*      gb   = (int*)(ws + O_GB);
  float*    tab  = (float*)(ws + O_TAB);

  k_prep<<<PREP_BLOCKS, 256, 0, stream>>>((int4*)ws, piece_x, tb, piece_emb,
                                          W_l, b_l, xs, cell_batch, gb);
  k_count<<<(NE / 4 + 255) / 256, 256, 0, stream>>>(tb, edge_src, edge_dst, cnt);
  k_layers4<<<NKEY / KPB, 256, 0, stream>>>(cell_emb, W_r, b_r, xs, att, conv_bias, tab);
  k_poolhead<<<NG, 256, 0, stream>>>(gb, cntu, tab,
                                     fc1_w, fc1_b, pol_w, pol_b,
                                     val_w, val_b, out);
}

// Round 9
// 59.520 us; speedup vs baseline: 1.2068x; 1.2068x over previous
//
#include <hip/hip_runtime.h>
#include <math.h>

#define NC 200000
#define NE 500000
#define NP 100000
#define NG 256
#define NLAYERS 4
#define NKEY 256          // key = (min(n0,15)<<4) | min(n1,15)
#define CLAMP 15
#define NSLOPE 0.2f
#define R 8               // count replicas, one per XCD

// workspace layout (bytes)
#define O_CNT 0u          // R*NC ints, packed n0=lo16 n1=hi16 (6,400,000 B)
#define O_TB  6400000u    // 3125 uints: piece type bits (12,800 B)
#define O_XS  6412800u    // 4096 f32: xs[(l*2+t)*512 + h*128 + d]
#define O_GB  6429184u    // 257 ints: per-graph cell ranges
#define O_TAB 6430336u    // NKEY*128 f32

// k_prep block partition
#define ZB   1563         // zero R*NC ints (400,000 int4)
#define TBB  13           // type-bit pack blocks
#define XSB  16           // xs GEMM blocks
#define GBB  782          // boundary-scan blocks
#define PREP_BLOCKS (ZB + TBB + XSB + GBB)

__device__ __forceinline__ float lrelu(float x) { return x > 0.f ? x : NSLOPE * x; }

// prep: zero cnt replicas; pack piece type bits; xs = piece_emb@W_l+b_l;
// gb = per-graph cell ranges via boundary scan of sorted cell_batch
__global__ void k_prep(int4* __restrict__ zbase,
                       const int* __restrict__ piece_x,
                       unsigned* __restrict__ tb,
                       const float* __restrict__ piece_emb,
                       const float* __restrict__ W_l,
                       const float* __restrict__ b_l,
                       float* __restrict__ xs,
                       const int* __restrict__ cell_batch,
                       int* __restrict__ gb) {
  int b = blockIdx.x, tid = threadIdx.x;
  if (b < ZB) {
    int i4 = b * 256 + tid;
    if (i4 < (R * NC) / 4) zbase[i4] = make_int4(0, 0, 0, 0);
  } else if (b < ZB + TBB) {
    int j = (b - ZB) * 256 + tid;                 // 3125 words of 32 pieces
    if (j < NP / 32) {
      unsigned w = 0;
      const int* p = piece_x + j * 32;
      #pragma unroll
      for (int k = 0; k < 32; ++k) w |= (unsigned)(p[k] & 1) << k;
      tb[j] = w;
    }
  } else if (b < ZB + TBB + XSB) {
    int idx = (b - ZB - TBB) * 256 + tid;         // 0..4095
    int l = idx >> 10, t = (idx >> 9) & 1, j = idx & 511;
    float acc = b_l[l * 512 + j];
    const float* pe = piece_emb + t * 128;
    const float* W = W_l + l * 65536;
    #pragma unroll 8
    for (int d = 0; d < 128; ++d) acc = fmaf(pe[d], W[d * 512 + j], acc);
    xs[idx] = acc;
  } else {
    int i = (b - ZB - TBB - XSB) * 256 + tid;
    if (i < NC) {
      int bi = cell_batch[i];
      int bn = (i + 1 < NC) ? cell_batch[i + 1] : NG;
      if (i == 0) for (int g = 0; g <= bi; ++g) gb[g] = 0;
      for (int g = bi + 1; g <= bn; ++g) gb[g] = i + 1;
    }
  }
}

// count edges per dst cell (packed by type); 4 edges/thread;
// replica pinned to this wave's XCD so atomics stay in the local L2
__global__ void __launch_bounds__(256)
k_count(const unsigned* __restrict__ tb,
        const int* __restrict__ esrc,
        const int* __restrict__ edst,
        int* __restrict__ cnt) {
  unsigned xcc;
  asm volatile("s_getreg_b32 %0, hwreg(HW_REG_XCC_ID)" : "=s"(xcc));
  int* base = cnt + (xcc & (R - 1)) * NC;
  int gid = blockIdx.x * blockDim.x + threadIdx.x;
  if (gid >= NE / 4) return;
  int4 s4 = *(const int4*)(esrc + gid * 4);
  int4 d4 = *(const int4*)(edst + gid * 4);
  int t0 = (tb[s4.x >> 5] >> (s4.x & 31)) & 1;
  int t1 = (tb[s4.y >> 5] >> (s4.y & 31)) & 1;
  int t2 = (tb[s4.z >> 5] >> (s4.z & 31)) & 1;
  int t3 = (tb[s4.w >> 5] >> (s4.w & 31)) & 1;
  atomicAdd(&base[d4.x], 1 << (t0 << 4));
  atomicAdd(&base[d4.y], 1 << (t1 << 4));
  atomicAdd(&base[d4.z], 1 << (t2 << 4));
  atomicAdd(&base[d4.w], 1 << (t3 << 4));
}

// all 4 GATv2 layers, ONE key per block, 512 threads (thread = one column).
// 256 blocks -> every CU busy, 8 waves/block for latency hiding.
__global__ void __launch_bounds__(512)
k_layers4(const float* __restrict__ cell_emb,
          const float* __restrict__ W_r, const float* __restrict__ b_r,
          const float* __restrict__ xs,  const float* __restrict__ att,
          const float* __restrict__ conv_bias,
          float* __restrict__ tab) {
  __shared__ float cell[128];
  __shared__ float part[8][2];      // per-wave partial sums [wave][type]
  __shared__ float wgt[8];          // [h]=w0, [4+h]=w1
  int tid = threadIdx.x;
  int key = blockIdx.x;
  int n0 = key >> 4, n1 = key & 15;
  if (tid < 128) cell[tid] = cell_emb[tid];
  __syncthreads();

  for (int l = 0; l < NLAYERS; ++l) {
    const float* Wl  = W_r + (size_t)l * 65536;
    const float* xsL = xs + l * 1024;
    // GEMV: acc = cell @ W_r[:, tid] + b_r[tid]
    float acc = b_r[l * 512 + tid];
    #pragma unroll 16
    for (int d = 0; d < 128; ++d)
      acc = fmaf(cell[d], Wl[d * 512 + tid], acc);
    float av = att[l * 512 + tid];
    float p0 = lrelu(xsL[tid] + acc) * av;         // type 0 contribution
    float p1 = lrelu(xsL[512 + tid] + acc) * av;   // type 1 contribution
    // 64-lane wave reduction
    #pragma unroll
    for (int m = 32; m >= 1; m >>= 1) {
      p0 += __shfl_xor(p0, m);
      p1 += __shfl_xor(p1, m);
    }
    int w = tid >> 6, lane = tid & 63;
    if (lane == 0) { part[w][0] = p0; part[w][1] = p1; }
    __syncthreads();
    if (tid < 4) {   // head tid: combine 2 waves, per-head 2-type softmax
      float L0 = part[2 * tid][0] + part[2 * tid + 1][0];
      float L1 = part[2 * tid][1] + part[2 * tid + 1][1];
      float ww0 = 0.f, ww1 = 0.f;
      if (n0 + n1 > 0) {
        float m = -1e30f;
        if (n0 > 0) m = L0;
        if (n1 > 0) m = fmaxf(m, L1);
        float e0 = (n0 > 0) ? (float)n0 * expf(L0 - m) : 0.f;
        float e1 = (n1 > 0) ? (float)n1 * expf(L1 - m) : 0.f;
        float inv = 1.f / (e0 + e1);
        ww0 = e0 * inv; ww1 = e1 * inv;
      }
      wgt[tid] = ww0; wgt[4 + tid] = ww1;
    }
    __syncthreads();
    if (tid < 128) {
      float o = conv_bias[l * 128 + tid];
      #pragma unroll
      for (int h = 0; h < 4; ++h)
        o += 0.25f * (wgt[h]     * xsL[h * 128 + tid] +
                      wgt[4 + h] * xsL[512 + h * 128 + tid]);
      o = fmaxf(o, 0.f);
      cell[tid] = o;
      if (l == NLAYERS - 1) tab[key * 128 + tid] = o;
    }
    __syncthreads();
  }
}

// per-graph pool via 256-key histogram (replica-summed) + MLP head
__global__ void __launch_bounds__(256)
k_poolhead(const int* __restrict__ gb, const unsigned* __restrict__ cnt,
           const float* __restrict__ tab,
           const float* __restrict__ fc1_w, const float* __restrict__ fc1_b,
           const float* __restrict__ pol_w, const float* __restrict__ pol_b,
           const float* __restrict__ val_w, const float* __restrict__ val_b,
           float* __restrict__ out) {
  __shared__ int hist[NKEY];
  __shared__ int klist[NKEY];
  __shared__ int wcnt[4];
  __shared__ float emb[128];
  __shared__ float hbuf[64];
  int g = blockIdx.x, tid = threadIdx.x;
  hist[tid] = 0;
  __syncthreads();
  int lo = gb[g], hi = gb[g + 1];
  for (int c = lo + tid; c < hi; c += 256) {
    unsigned v = 0;
    #pragma unroll
    for (int r = 0; r < R; ++r) v += cnt[c + r * NC];
    int n0 = min((int)(v & 0xffffu), CLAMP);
    int n1 = min((int)(v >> 16), CLAMP);
    atomicAdd(&hist[(n0 << 4) | n1], 1);
  }
  __syncthreads();
  // deterministic ordered compaction of present keys
  unsigned long long m = __ballot(hist[tid] != 0);
  int w = tid >> 6, lane = tid & 63;
  if (lane == 0) wcnt[w] = __popcll(m);
  __syncthreads();
  int basep = 0;
  #pragma unroll
  for (int i = 0; i < 4; ++i) if (i < w) basep += wcnt[i];
  if (hist[tid] != 0)
    klist[basep + __popcll(m & ((1ull << lane) - 1ull))] = tid;
  __syncthreads();
  int kn = wcnt[0] + wcnt[1] + wcnt[2] + wcnt[3];
  if (tid < 128) {
    float acc = 0.f;
    for (int i = 0; i < kn; ++i) {
      int k = klist[i];
      acc = fmaf((float)hist[k], tab[k * 128 + tid], acc);
    }
    emb[tid] = acc / fmaxf((float)(hi - lo), 1.f);
  }
  __syncthreads();
  if (tid < 64) {
    float a = fc1_b[tid];
    #pragma unroll 8
    for (int d = 0; d < 128; ++d) a = fmaf(emb[d], fc1_w[d * 64 + tid], a);
    hbuf[tid] = fmaxf(a, 0.f);
  }
  __syncthreads();
  if (tid < 8) {
    float p = pol_b[tid];
    #pragma unroll
    for (int k = 0; k < 64; ++k) p = fmaf(hbuf[k], pol_w[k * 8 + tid], p);
    out[g * 8 + tid] = p;
  } else if (tid == 8) {
    float v = val_b[0];
    #pragma unroll
    for (int k = 0; k < 64; ++k) v = fmaf(hbuf[k], val_w[k], v);
    out[NG * 8 + g] = tanhf(v);
  }
}

extern "C" void kernel_launch(void* const* d_in, const int* in_sizes, int n_in,
                              void* d_out, int out_size, void* d_ws, size_t ws_size,
                              hipStream_t stream) {
  (void)in_sizes; (void)n_in; (void)out_size; (void)ws_size;
  const int*   piece_x   = (const int*)d_in[1];
  const int*   edge_src  = (const int*)d_in[2];
  const int*   edge_dst  = (const int*)d_in[3];
  const int*   cell_batch= (const int*)d_in[4];
  const float* cell_emb  = (const float*)d_in[5];
  const float* piece_emb = (const float*)d_in[6];
  const float* W_l       = (const float*)d_in[7];
  const float* b_l       = (const float*)d_in[8];
  const float* W_r       = (const float*)d_in[9];
  const float* b_r       = (const float*)d_in[10];
  const float* att       = (const float*)d_in[11];
  const float* conv_bias = (const float*)d_in[12];
  const float* fc1_w     = (const float*)d_in[13];
  const float* fc1_b     = (const float*)d_in[14];
  const float* pol_w     = (const float*)d_in[15];
  const float* pol_b     = (const float*)d_in[16];
  const float* val_w     = (const float*)d_in[17];
  const float* val_b     = (const float*)d_in[18];
  float* out = (float*)d_out;

  char* ws = (char*)d_ws;
  int*      cnt  = (int*)(ws + O_CNT);
  unsigned* cntu = (unsigned*)(ws + O_CNT);
  unsigned* tb   = (unsigned*)(ws + O_TB);
  float*    xs   = (float*)(ws + O_XS);
  int*      gb   = (int*)(ws + O_GB);
  float*    tab  = (float*)(ws + O_TAB);

  k_prep<<<PREP_BLOCKS, 256, 0, stream>>>((int4*)ws, piece_x, tb, piece_emb,
                                          W_l, b_l, xs, cell_batch, gb);
  k_count<<<(NE / 4 + 255) / 256, 256, 0, stream>>>(tb, edge_src, edge_dst, cnt);
  k_layers4<<<NKEY, 512, 0, stream>>>(cell_emb, W_r, b_r, xs, att, conv_bias, tab);
  k_poolhead<<<NG, 256, 0, stream>>>(gb, cntu, tab,
                                     fc1_w, fc1_b, pol_w, pol_b,
                                     val_w, val_b, out);
}